// Round 6
// baseline (267.946 us; speedup 1.0000x reference)
//
#include <hip/hip_runtime.h>
#include <hip/hip_bf16.h>

// DynamicSlidingWindowAttention — flash attention, bf16 MFMA, gfx950.
// R6: BARRIER-FREE per-wave design. Prepass stores K as bf16 [b,h,t,d] and
// V as bf16 transposed [b,h,d,t] in d_ws; MFMA A/B fragments are 16B
// contiguous in those layouts, so each wave loads fragments DIRECTLY from
// global (L2/L3) — no LDS staging, no __syncthreads at all. One wave per
// 16-row item (4096 items), per-wave atomic work-stealing. Static-max
// softmax in log2 domain (C=16 in acc init); l via per-lane partials with
// one end-of-item cross-quad reduce; P C->A through per-wave LDS (9 KB/block).
// Layouts (m89/m91/m120-verified):
//   mfma_f32_16x16x32_bf16: A[m=lane&15][k=quad*8+j], B[k=quad*8+j][n=lane&15],
//   C/D: col=lane&15, row=quad*4+reg.

constexpr int Bc = 2, Hc = 16, Tc = 2048, Dc = 64;
constexpr int BK = 64;
constexpr int PSTR = 72;                       // P LDS row stride (ushort)
constexpr int N_ITEMS = Bc * Hc * (Tc / 16);   // 4096 (16-row items)
constexpr float QSCALE = 0.125f * 1.44269504088896340736f;  // 1/sqrt(d)*log2e
constexpr float CMAX = 16.0f;                  // static softmax max (log2)

// d_ws layout (bytes): [0,4) counter | [256,+8MiB) K bf16 | then V^T bf16
constexpr size_t KB_OFF = 256;
constexpr size_t VB_OFF = 256 + (size_t)Bc * Hc * Tc * Dc * 2;
constexpr int HEADE = Tc * Dc;

typedef __attribute__((ext_vector_type(8))) short short8;
typedef __attribute__((ext_vector_type(4))) float float4v;

#if defined(__has_builtin)
#if __has_builtin(__builtin_amdgcn_exp2f)
#define EXP2 __builtin_amdgcn_exp2f
#endif
#endif
#ifndef EXP2
#define EXP2 exp2f
#endif

__device__ inline unsigned f2bf_u(float f) {
    union { float f; unsigned u; } v; v.f = f;
    return (v.u + 0x7fffu + ((v.u >> 16) & 1u)) >> 16;   // RNE
}

__device__ inline short8 pack8(const float* t) {
    short8 r;
#pragma unroll
    for (int j = 0; j < 8; j++) r[j] = (short)f2bf_u(t[j]);
    return r;
}

__device__ inline unsigned pk_bf16(float a, float b) {
    __hip_bfloat162 h = __float22bfloat162_rn(make_float2(a, b));
    union { __hip_bfloat162 h; unsigned u; } v; v.h = h;
    return v.u;
}

// ---- pre-pass: K convert + V transpose-convert ----
__global__ __launch_bounds__(256)
void preconv_kernel(const float* __restrict__ K, const float* __restrict__ V,
                    unsigned short* __restrict__ Kb, unsigned short* __restrict__ Vtb) {
    const int blk = blockIdx.x;
    const int tid = threadIdx.x;
    if (blk < 2048) {
        const int base = blk * 2048 + tid * 8;
        float4v a = *(const float4v*)(K + base);
        float4v b = *(const float4v*)(K + base + 4);
        float t[8] = {a[0], a[1], a[2], a[3], b[0], b[1], b[2], b[3]};
        *(short8*)(Kb + base) = pack8(t);
    } else {
        __shared__ float tile[64][65];
        const int blk2 = blk - 2048;
        const int bh = blk2 >> 5;
        const int t0 = (blk2 & 31) * 64;
        const float* src = V + (size_t)bh * HEADE + (size_t)t0 * Dc;
#pragma unroll
        for (int i = 0; i < 4; i++) {
            const int r = (tid >> 4) + i * 16;
            const int d4 = (tid & 15) * 4;
            float4v v4 = *(const float4v*)(src + r * Dc + d4);
            tile[r][d4] = v4[0]; tile[r][d4 + 1] = v4[1];
            tile[r][d4 + 2] = v4[2]; tile[r][d4 + 3] = v4[3];
        }
        __syncthreads();
        unsigned short* dst = Vtb + (size_t)bh * HEADE + t0;
#pragma unroll
        for (int i = 0; i < 2; i++) {
            const int d = (tid >> 3) + 32 * i;
            const int c = tid & 7;
            float t[8];
#pragma unroll
            for (int j = 0; j < 8; j++) t[j] = tile[c * 8 + j][d];
            *(short8*)(dst + (size_t)d * Tc + c * 8) = pack8(t);
        }
    }
}

__global__ __launch_bounds__(256, 4)
void dswa_kernel(const float* __restrict__ Q,
                 const unsigned short* __restrict__ Kb,
                 const unsigned short* __restrict__ Vtb,
                 const int* __restrict__ wsz,
                 float* __restrict__ O, unsigned* __restrict__ counter) {
    __shared__ __align__(16) unsigned short Pbuf[4 * 16 * PSTR];  // per-wave P

    const int tid  = threadIdx.x;
    const int wave = tid >> 6;
    const int lane = tid & 63;
    const int quad = lane >> 4;
    const int l16  = lane & 15;

    unsigned short* Pl = &Pbuf[wave * 16 * PSTR];

    for (;;) {
        // ---- per-wave work stealing ----
        int idx;
        if (lane == 0) idx = (int)atomicAdd(counter, 1u);
        idx = __shfl(idx, 0);
        if (idx >= N_ITEMS) return;

        // heavy-first decode: h descending (largest window), qc descending
        const int b  = idx & 1;
        const int qc = 127 - ((idx >> 1) & 127);
        const int h  = 15 - (idx >> 8);
        const int q0 = qc * 16;
        const int win = wsz[h];

        const size_t headoff = (size_t)(b * Hc + h) * HEADE;
        const float* Qp = Q + headoff;
        const unsigned short* Kbh = Kb + headoff;
        const unsigned short* Vbh = Vtb + headoff;
        float* Op = O + headoff;

        // ---- Q fragment (rows q0+l16), pre-scaled (log2 domain) ----
        short8 qf[2];
#pragma unroll
        for (int c = 0; c < 2; c++) {
            const float* src = Qp + (size_t)(q0 + l16) * Dc + c * 32 + quad * 8;
            float4v a = *(const float4v*)src;
            float4v d4 = *(const float4v*)(src + 4);
            float t[8] = {a[0]*QSCALE, a[1]*QSCALE, a[2]*QSCALE, a[3]*QSCALE,
                          d4[0]*QSCALE, d4[1]*QSCALE, d4[2]*QSCALE, d4[3]*QSCALE};
            qf[c] = pack8(t);
        }

        float4v acc[4];
#pragma unroll
        for (int nb = 0; nb < 4; nb++) acc[nb] = (float4v){0.f, 0.f, 0.f, 0.f};
        float lp = 0.0f;   // per-lane l partial (qrow=l16, keys of this quad)

        const int kv_lo = (max(0, q0 - win)) & ~(BK - 1);
        const int n_tiles = ((q0 + 15 - kv_lo) >> 6) + 1;

        for (int ti = 0; ti < n_tiles; ++ti) {
            const int kv0 = kv_lo + ti * BK;

            // ---- K fragments direct from global (16B/lane, L2-resident) ----
            short8 kf[8];   // [mb*2+ch]
#pragma unroll
            for (int mb = 0; mb < 4; mb++)
#pragma unroll
                for (int ch = 0; ch < 2; ch++)
                    kf[mb * 2 + ch] = *(const short8*)
                        (Kbh + (size_t)(kv0 + mb * 16 + l16) * Dc + ch * 32 + quad * 8);

            // ---- S^T = K Q^T - CMAX ----
            float4v sT[4];
#pragma unroll
            for (int mb = 0; mb < 4; mb++) {
                float4v c = {-CMAX, -CMAX, -CMAX, -CMAX};
                c = __builtin_amdgcn_mfma_f32_16x16x32_bf16(kf[mb * 2 + 0], qf[0], c, 0, 0, 0);
                c = __builtin_amdgcn_mfma_f32_16x16x32_bf16(kf[mb * 2 + 1], qf[1], c, 0, 0, 0);
                sT[mb] = c;
            }

            // ---- V fragments (issue early; latency overlaps softmax) ----
            short8 vf[8];   // [nb*2+ch]
#pragma unroll
            for (int nb = 0; nb < 4; nb++)
#pragma unroll
                for (int ch = 0; ch < 2; ch++)
                    vf[nb * 2 + ch] = *(const short8*)
                        (Vbh + (size_t)(nb * 16 + l16) * Tc + kv0 + ch * 32 + quad * 8);

            // ---- mask on boundary tiles only (wave-uniform test) ----
            const bool interior = (kv0 + 63 <= q0) && (kv0 >= q0 + 15 - win);
            if (!interior) {
                const int dbase = q0 + l16 - kv0 - quad * 4;
#pragma unroll
                for (int mb = 0; mb < 4; mb++)
#pragma unroll
                    for (int r = 0; r < 4; r++) {
                        const unsigned diff = (unsigned)(dbase - mb * 16 - r);
                        sT[mb][r] = (diff <= (unsigned)win) ? sT[mb][r] : -3.0e38f;
                    }
            }

            // ---- p = exp2(s'); accumulate l partial; pack P to LDS ----
#pragma unroll
            for (int mb = 0; mb < 4; mb++) {
                float p0 = EXP2(sT[mb][0]);
                float p1 = EXP2(sT[mb][1]);
                float p2 = EXP2(sT[mb][2]);
                float p3 = EXP2(sT[mb][3]);
                lp += (p0 + p1) + (p2 + p3);
                unsigned* dst = (unsigned*)&Pl[l16 * PSTR + mb * 16 + quad * 4];
                dst[0] = pk_bf16(p0, p1);
                dst[1] = pk_bf16(p2, p3);
            }

            // ---- P (C-layout) -> A-layout via per-wave LDS round trip ----
            __asm__ volatile("" ::: "memory");
            short8 pf[2];
#pragma unroll
            for (int ch = 0; ch < 2; ch++)
                pf[ch] = *(short8*)&Pl[l16 * PSTR + ch * 32 + quad * 8];

            // ---- O += P V ----
#pragma unroll
            for (int nb = 0; nb < 4; nb++) {
                acc[nb] = __builtin_amdgcn_mfma_f32_16x16x32_bf16(pf[0], vf[nb * 2 + 0], acc[nb], 0, 0, 0);
                acc[nb] = __builtin_amdgcn_mfma_f32_16x16x32_bf16(pf[1], vf[nb * 2 + 1], acc[nb], 0, 0, 0);
            }
        }

        // ---- finalize: one cross-quad l reduction, normalize, store ----
        lp += __shfl_xor(lp, 16);
        lp += __shfl_xor(lp, 32);   // lanes 0..15 (any quad): l for qrow=l16
#pragma unroll
        for (int r = 0; r < 4; r++) {
            const float inv = 1.0f / __shfl(lp, quad * 4 + r);
            float* dst = Op + (size_t)(q0 + quad * 4 + r) * Dc;
#pragma unroll
            for (int nb = 0; nb < 4; nb++)
                dst[nb * 16 + l16] = acc[nb][r] * inv;
        }
    }
}

extern "C" void kernel_launch(void* const* d_in, const int* in_sizes, int n_in,
                              void* d_out, int out_size, void* d_ws, size_t ws_size,
                              hipStream_t stream) {
    (void)in_sizes; (void)n_in; (void)ws_size; (void)out_size;
    const float* Q = (const float*)d_in[0];
    const float* K = (const float*)d_in[1];
    const float* V = (const float*)d_in[2];
    const int* wsz = (const int*)d_in[3];
    float* Out = (float*)d_out;

    unsigned* counter = (unsigned*)d_ws;
    unsigned short* Kb  = (unsigned short*)((char*)d_ws + KB_OFF);
    unsigned short* Vtb = (unsigned short*)((char*)d_ws + VB_OFF);

    hipMemsetAsync(counter, 0, sizeof(unsigned), stream);
    preconv_kernel<<<dim3(3072), dim3(256), 0, stream>>>(K, V, Kb, Vtb);
    // 1024 blocks x 4 waves = 4096 workers = N_ITEMS; barrier-free body.
    dswa_kernel<<<dim3(1024), dim3(256), 0, stream>>>(Q, Kb, Vtb, wsz, Out, counter);
}

// Round 7
// 158.908 us; speedup vs baseline: 1.6862x; 1.6862x over previous
//
#include <hip/hip_runtime.h>
#include <hip/hip_bf16.h>

// DynamicSlidingWindowAttention — flash attention, bf16 MFMA, gfx950.
// R7 = R5 structure (persistent 512-thread blocks, work-stealing heavy-first,
// 2-way KV split, prestaged bf16 K / V^T in d_ws, register-prefetch, static-
// max softmax in log2 domain) with:
//   * XOR-swizzled LDS (stride 64, col ^= (row&7)<<3) instead of +8 padding
//     -> 49.2 KB/block -> 3 blocks/CU (24 waves/CU, was 2/16).
//   * l via per-lane partial sums + one end-of-item cross-quad reduce
//     (drops the ones-row MFMA and its LDS rows).
// R6 lesson: direct-from-global fragments (no LDS staging) lose badly —
// per-wave loads forfeit the 8-wave sharing and blow up HBM traffic.
// Layouts (m89/m91/m120-verified):
//   mfma_f32_16x16x32_bf16: A[m=lane&15][k=quad*8+j], B[k=quad*8+j][n=lane&15],
//   C/D: col=lane&15, row=quad*4+reg.

constexpr int Bc = 2, Hc = 16, Tc = 2048, Dc = 64;
constexpr int BQ = 64;
constexpr int BK = 64;
constexpr int N_ITEMS = Bc * Hc * (Tc / BQ);   // 1024
constexpr float QSCALE = 0.125f * 1.44269504088896340736f;  // 1/sqrt(d)*log2e
constexpr float CMAX = 16.0f;   // static softmax max (log2 domain)

// d_ws layout (bytes): [0,4) counter | [256,+8MiB) K bf16 | then V^T bf16
constexpr size_t KB_OFF = 256;
constexpr size_t VB_OFF = 256 + (size_t)Bc * Hc * Tc * Dc * 2;
constexpr int HEADE = Tc * Dc;

// LDS (ushort units): K 2x4096 | V^T 2x4096 | P 8x1024 | item broadcast
constexpr int KOFF = 0;        // + g*4096
constexpr int VOFF = 8192;     // + g*4096
constexpr int POFF = 16384;    // + wave*1024
constexpr int IBOFF = 24576;   // total 49160 B -> 3 blocks/CU

typedef __attribute__((ext_vector_type(8))) short short8;
typedef __attribute__((ext_vector_type(4))) float float4v;

#if defined(__has_builtin)
#if __has_builtin(__builtin_amdgcn_exp2f)
#define EXP2 __builtin_amdgcn_exp2f
#endif
#endif
#ifndef EXP2
#define EXP2 exp2f
#endif

__device__ inline unsigned f2bf_u(float f) {
    union { float f; unsigned u; } v; v.f = f;
    return (v.u + 0x7fffu + ((v.u >> 16) & 1u)) >> 16;   // RNE
}

__device__ inline short8 pack8(const float* t) {
    short8 r;
#pragma unroll
    for (int j = 0; j < 8; j++) r[j] = (short)f2bf_u(t[j]);
    return r;
}

__device__ inline unsigned pk_bf16(float a, float b) {
    __hip_bfloat162 h = __float22bfloat162_rn(make_float2(a, b));
    union { __hip_bfloat162 h; unsigned u; } v; v.h = h;
    return v.u;
}

// XOR swizzle: row-major stride 64 (ushorts), 8-element granule rotated by
// (row&7) — kills the 16-way bank conflicts of unpadded stride-64 while
// keeping 16B-contiguous fragment reads. Writes/reads both use (row&7).
__device__ inline int swz(int row, int col8) {
    return row * 64 + (col8 ^ ((row & 7) << 3));
}

// ---- pre-pass: K convert + V transpose-convert ----
__global__ __launch_bounds__(256)
void preconv_kernel(const float* __restrict__ K, const float* __restrict__ V,
                    unsigned short* __restrict__ Kb, unsigned short* __restrict__ Vtb) {
    const int blk = blockIdx.x;
    const int tid = threadIdx.x;
    if (blk < 2048) {
        const int base = blk * 2048 + tid * 8;
        float4v a = *(const float4v*)(K + base);
        float4v b = *(const float4v*)(K + base + 4);
        float t[8] = {a[0], a[1], a[2], a[3], b[0], b[1], b[2], b[3]};
        *(short8*)(Kb + base) = pack8(t);
    } else {
        __shared__ float tile[64][65];
        const int blk2 = blk - 2048;
        const int bh = blk2 >> 5;
        const int t0 = (blk2 & 31) * 64;
        const float* src = V + (size_t)bh * HEADE + (size_t)t0 * Dc;
#pragma unroll
        for (int i = 0; i < 4; i++) {
            const int r = (tid >> 4) + i * 16;
            const int d4 = (tid & 15) * 4;
            float4v v4 = *(const float4v*)(src + r * Dc + d4);
            tile[r][d4] = v4[0]; tile[r][d4 + 1] = v4[1];
            tile[r][d4 + 2] = v4[2]; tile[r][d4 + 3] = v4[3];
        }
        __syncthreads();
        unsigned short* dst = Vtb + (size_t)bh * HEADE + t0;
#pragma unroll
        for (int i = 0; i < 2; i++) {
            const int d = (tid >> 3) + 32 * i;
            const int c = tid & 7;
            float t[8];
#pragma unroll
            for (int j = 0; j < 8; j++) t[j] = tile[c * 8 + j][d];
            *(short8*)(dst + (size_t)d * Tc + c * 8) = pack8(t);
        }
    }
}

__global__ __launch_bounds__(512, 6)
void dswa_kernel(const float* __restrict__ Q,
                 const unsigned short* __restrict__ Kb,
                 const unsigned short* __restrict__ Vtb,
                 const int* __restrict__ wsz,
                 float* __restrict__ O, unsigned* __restrict__ counter) {
    __shared__ __align__(16) unsigned short LDS[24576 + 8];

    const int tid  = threadIdx.x;
    const int g    = tid >> 8;          // kv-split group 0/1
    const int ltid = tid & 255;
    const int wave = tid >> 6;
    const int wv   = wave & 3;          // q-row group
    const int lane = tid & 63;
    const int quad = lane >> 4;
    const int l16  = lane & 15;
    const int sw8  = (l16 & 7) << 3;    // fragment-read swizzle term

    unsigned short* Kl = &LDS[KOFF + g * 4096];
    unsigned short* Vt = &LDS[VOFF + g * 4096];
    unsigned short* Pl = &LDS[POFF + wave * 1024];
    int* ib = (int*)&LDS[IBOFF];

    const int srow = ltid >> 3;         // staging row 0..31 (+32)
    const int scol = (ltid & 7) * 8;

    for (;;) {
        if (tid == 0) *ib = (int)atomicAdd(counter, 1u);
        __syncthreads();
        const int idx = *ib;
        if (idx >= N_ITEMS) break;

        // heavy-first: h descending (largest window first), qt descending
        const int b  = idx & 1;
        const int qt = 31 - ((idx >> 1) & 31);
        const int h  = 15 - (idx >> 6);
        const int q0 = qt * BQ;
        const int win = wsz[h];

        const size_t headoff = (size_t)(b * Hc + h) * HEADE;
        const float* Qp = Q + headoff;
        const unsigned short* Kbh = Kb + headoff;
        const unsigned short* Vbh = Vtb + headoff;
        float* Op = O + headoff;

        // ---- Q fragments, pre-scaled (log2 domain) ----
        short8 qf[2];
        {
            const int qrow = q0 + wv * 16 + l16;
#pragma unroll
            for (int c = 0; c < 2; c++) {
                const float* src = Qp + (size_t)qrow * Dc + c * 32 + quad * 8;
                float4v a = *(const float4v*)src;
                float4v d4 = *(const float4v*)(src + 4);
                float t[8] = {a[0]*QSCALE, a[1]*QSCALE, a[2]*QSCALE, a[3]*QSCALE,
                              d4[0]*QSCALE, d4[1]*QSCALE, d4[2]*QSCALE, d4[3]*QSCALE};
                qf[c] = pack8(t);
            }
        }

        float4v acc[4];   // O accumulator (unnormalized)
#pragma unroll
        for (int nb = 0; nb < 4; nb++) acc[nb] = (float4v){0.f, 0.f, 0.f, 0.f};
        float lp = 0.0f;  // per-lane l partial (qrow = l16; this quad's keys)

        const int kv_lo = (max(0, q0 - win)) & ~(BK - 1);
        const int n_tiles = (q0 + BQ - kv_lo) >> 6;
        const int IT = (n_tiles + 1) >> 1;

        const int rw0 = q0 + wv * 16;
        const int rg_rel0 = rw0 + l16 - quad * 4;

        // ---- prologue prefetch: tile g into registers ----
        short8 kr0, kr1, vr0, vr1;
        if (g < n_tiles) {
            const int kv0 = kv_lo + g * BK;
            kr0 = *(const short8*)(Kbh + (size_t)(kv0 + srow) * Dc + scol);
            kr1 = *(const short8*)(Kbh + (size_t)(kv0 + srow + 32) * Dc + scol);
            vr0 = *(const short8*)(Vbh + (size_t)srow * Tc + kv0 + scol);
            vr1 = *(const short8*)(Vbh + (size_t)(srow + 32) * Tc + kv0 + scol);
        }

        for (int t = 0; t < IT; ++t) {
            const int ti = g + 2 * t;
            const bool act = ti < n_tiles;
            const int kv0 = kv_lo + ti * BK;

            __syncthreads();   // prev iteration's LDS reads complete

            if (act) {
                *(short8*)&Kl[swz(srow, scol)] = kr0;
                *(short8*)&Kl[swz(srow + 32, scol)] = kr1;
                *(short8*)&Vt[swz(srow, scol)] = vr0;
                *(short8*)&Vt[swz(srow + 32, scol)] = vr1;
            }
            __syncthreads();

            // prefetch next tile (overlaps compute)
            const int tn = ti + 2;
            if (tn < n_tiles) {
                const int kvn = kv_lo + tn * BK;
                kr0 = *(const short8*)(Kbh + (size_t)(kvn + srow) * Dc + scol);
                kr1 = *(const short8*)(Kbh + (size_t)(kvn + srow + 32) * Dc + scol);
                vr0 = *(const short8*)(Vbh + (size_t)srow * Tc + kvn + scol);
                vr1 = *(const short8*)(Vbh + (size_t)(srow + 32) * Tc + kvn + scol);
            }

            if (act) {
                // ---- S^T = K Q^T - CMAX (acc-init fold) ----
                float4v sT[4];
#pragma unroll
                for (int mb = 0; mb < 4; mb++) {
                    float4v c = {-CMAX, -CMAX, -CMAX, -CMAX};
#pragma unroll
                    for (int ch = 0; ch < 2; ch++) {
                        short8 kf = *(short8*)&Kl[(mb * 16 + l16) * 64 +
                                                  ((ch * 32 + quad * 8) ^ sw8)];
                        c = __builtin_amdgcn_mfma_f32_16x16x32_bf16(kf, qf[ch], c, 0, 0, 0);
                    }
                    sT[mb] = c;
                }

                // ---- mask only on boundary tiles (wave-uniform test) ----
                const bool interior = (rw0 >= kv0 + 63) && (rw0 + 15 - kv0 <= win);
                if (!interior) {
                    const int dbase = rg_rel0 - kv0;
#pragma unroll
                    for (int mb = 0; mb < 4; mb++)
#pragma unroll
                        for (int r = 0; r < 4; r++) {
                            const unsigned diff = (unsigned)(dbase - mb * 16 - r);
                            sT[mb][r] = (diff <= (unsigned)win) ? sT[mb][r] : -3.0e38f;
                        }
                }

                // ---- p = exp2(s'); l partial; pack P to LDS ----
#pragma unroll
                for (int mb = 0; mb < 4; mb++) {
                    float p0 = EXP2(sT[mb][0]);
                    float p1 = EXP2(sT[mb][1]);
                    float p2 = EXP2(sT[mb][2]);
                    float p3 = EXP2(sT[mb][3]);
                    lp += (p0 + p1) + (p2 + p3);
                    unsigned* dst = (unsigned*)&Pl[l16 * 64 +
                                                   ((mb * 16 + quad * 4) ^ sw8)];
                    dst[0] = pk_bf16(p0, p1);
                    dst[1] = pk_bf16(p2, p3);
                }

                // ---- P (C-layout) -> A-layout via per-wave LDS ----
                __asm__ volatile("" ::: "memory");
                short8 pf[2];
#pragma unroll
                for (int ch = 0; ch < 2; ch++)
                    pf[ch] = *(short8*)&Pl[l16 * 64 + ((ch * 32 + quad * 8) ^ sw8)];

                // ---- O += P V ----
#pragma unroll
                for (int nb = 0; nb < 4; nb++) {
#pragma unroll
                    for (int ch = 0; ch < 2; ch++) {
                        short8 vf = *(short8*)&Vt[(nb * 16 + l16) * 64 +
                                                  ((ch * 32 + quad * 8) ^ sw8)];
                        acc[nb] = __builtin_amdgcn_mfma_f32_16x16x32_bf16(pf[ch], vf, acc[nb], 0, 0, 0);
                    }
                }
            }
        }

        // ---- l: one cross-quad reduce (all quads end up with full row sum) --
        lp += __shfl_xor(lp, 16);
        lp += __shfl_xor(lp, 32);

        // ---- merge the two KV-split partials (pure adds), store ----
        __syncthreads();
        float* fl = (float*)LDS;   // 64 rows x stride 66: cols 0..63 = O, 64 = l
        if (g == 1) {
            if (quad == 0) fl[(wv * 16 + l16) * 66 + 64] = lp;
#pragma unroll
            for (int r = 0; r < 4; r++) {
                const int row = wv * 16 + quad * 4 + r;
#pragma unroll
                for (int nb = 0; nb < 4; nb++)
                    fl[row * 66 + nb * 16 + l16] = acc[nb][r];
            }
        }
        __syncthreads();
        if (g == 0) {
#pragma unroll
            for (int r = 0; r < 4; r++) {
                const int row = wv * 16 + quad * 4 + r;
                const float l0 = __shfl(lp, quad * 4 + r);
                const float lt = l0 + fl[row * 66 + 64];
                const float inv = 1.0f / lt;
                float* dst = Op + (size_t)(q0 + row) * Dc;
#pragma unroll
                for (int nb = 0; nb < 4; nb++)
                    dst[nb * 16 + l16] = (acc[nb][r] + fl[row * 66 + nb * 16 + l16]) * inv;
            }
        }
        // next item's post-atomic barrier protects fl before reuse
    }
}

extern "C" void kernel_launch(void* const* d_in, const int* in_sizes, int n_in,
                              void* d_out, int out_size, void* d_ws, size_t ws_size,
                              hipStream_t stream) {
    (void)in_sizes; (void)n_in; (void)ws_size; (void)out_size;
    const float* Q = (const float*)d_in[0];
    const float* K = (const float*)d_in[1];
    const float* V = (const float*)d_in[2];
    const int* wsz = (const int*)d_in[3];
    float* Out = (float*)d_out;

    unsigned* counter = (unsigned*)d_ws;
    unsigned short* Kb  = (unsigned short*)((char*)d_ws + KB_OFF);
    unsigned short* Vtb = (unsigned short*)((char*)d_ws + VB_OFF);

    hipMemsetAsync(counter, 0, sizeof(unsigned), stream);
    preconv_kernel<<<dim3(3072), dim3(256), 0, stream>>>(K, V, Kb, Vtb);
    // 768 blocks = 3 blocks/CU x 256 CU (LDS 49.2 KB); work-stealing body.
    dswa_kernel<<<dim3(768), dim3(512), 0, stream>>>(Q, Kb, Vtb, wsz, Out, counter);
}

// Round 8
// 128.697 us; speedup vs baseline: 2.0820x; 1.2347x over previous
//
#include <hip/hip_runtime.h>
#include <hip/hip_bf16.h>

// DynamicSlidingWindowAttention — flash attention, bf16 MFMA, gfx950.
// R8 = R7 with the spill fixed: __launch_bounds__(512,4) (VGPR cap 128, not
// 84). R7's launch_bounds(512,6) forced VGPR<=84 -> scratch spills
// (WRITE_SIZE 16->90 MB, VALUBusy 14%). Swizzle + 3 blocks/CU both landed
// (conflicts 4.4M->0.95M, occupancy 46%) — kept.
// Structure: persistent 512-thread blocks, work-stealing heavy-first, 2-way
// KV split, prestaged bf16 K / V^T in d_ws, register-prefetch, static-max
// softmax in log2 domain, XOR-swizzled LDS (49.2 KB -> 3 blocks/CU).
// Layouts (m89/m91/m120-verified):
//   mfma_f32_16x16x32_bf16: A[m=lane&15][k=quad*8+j], B[k=quad*8+j][n=lane&15],
//   C/D: col=lane&15, row=quad*4+reg.

constexpr int Bc = 2, Hc = 16, Tc = 2048, Dc = 64;
constexpr int BQ = 64;
constexpr int BK = 64;
constexpr int N_ITEMS = Bc * Hc * (Tc / BQ);   // 1024
constexpr float QSCALE = 0.125f * 1.44269504088896340736f;  // 1/sqrt(d)*log2e
constexpr float CMAX = 16.0f;   // static softmax max (log2 domain)

// d_ws layout (bytes): [0,4) counter | [256,+8MiB) K bf16 | then V^T bf16
constexpr size_t KB_OFF = 256;
constexpr size_t VB_OFF = 256 + (size_t)Bc * Hc * Tc * Dc * 2;
constexpr int HEADE = Tc * Dc;

// LDS (ushort units): K 2x4096 | V^T 2x4096 | P 8x1024 | item broadcast
constexpr int KOFF = 0;        // + g*4096
constexpr int VOFF = 8192;     // + g*4096
constexpr int POFF = 16384;    // + wave*1024
constexpr int IBOFF = 24576;   // total 49160 B -> 3 blocks/CU

typedef __attribute__((ext_vector_type(8))) short short8;
typedef __attribute__((ext_vector_type(4))) float float4v;

#if defined(__has_builtin)
#if __has_builtin(__builtin_amdgcn_exp2f)
#define EXP2 __builtin_amdgcn_exp2f
#endif
#endif
#ifndef EXP2
#define EXP2 exp2f
#endif

__device__ inline unsigned f2bf_u(float f) {
    union { float f; unsigned u; } v; v.f = f;
    return (v.u + 0x7fffu + ((v.u >> 16) & 1u)) >> 16;   // RNE
}

__device__ inline short8 pack8(const float* t) {
    short8 r;
#pragma unroll
    for (int j = 0; j < 8; j++) r[j] = (short)f2bf_u(t[j]);
    return r;
}

__device__ inline unsigned pk_bf16(float a, float b) {
    __hip_bfloat162 h = __float22bfloat162_rn(make_float2(a, b));
    union { __hip_bfloat162 h; unsigned u; } v; v.h = h;
    return v.u;
}

// XOR swizzle: row-major stride 64 (ushorts), 8-element granule rotated by
// (row&7) — breaks the 16-way bank conflicts of unpadded stride-64 while
// keeping 16B-contiguous fragment reads.
__device__ inline int swz(int row, int col8) {
    return row * 64 + (col8 ^ ((row & 7) << 3));
}

// ---- pre-pass: K convert + V transpose-convert ----
__global__ __launch_bounds__(256)
void preconv_kernel(const float* __restrict__ K, const float* __restrict__ V,
                    unsigned short* __restrict__ Kb, unsigned short* __restrict__ Vtb) {
    const int blk = blockIdx.x;
    const int tid = threadIdx.x;
    if (blk < 2048) {
        const int base = blk * 2048 + tid * 8;
        float4v a = *(const float4v*)(K + base);
        float4v b = *(const float4v*)(K + base + 4);
        float t[8] = {a[0], a[1], a[2], a[3], b[0], b[1], b[2], b[3]};
        *(short8*)(Kb + base) = pack8(t);
    } else {
        __shared__ float tile[64][65];
        const int blk2 = blk - 2048;
        const int bh = blk2 >> 5;
        const int t0 = (blk2 & 31) * 64;
        const float* src = V + (size_t)bh * HEADE + (size_t)t0 * Dc;
#pragma unroll
        for (int i = 0; i < 4; i++) {
            const int r = (tid >> 4) + i * 16;
            const int d4 = (tid & 15) * 4;
            float4v v4 = *(const float4v*)(src + r * Dc + d4);
            tile[r][d4] = v4[0]; tile[r][d4 + 1] = v4[1];
            tile[r][d4 + 2] = v4[2]; tile[r][d4 + 3] = v4[3];
        }
        __syncthreads();
        unsigned short* dst = Vtb + (size_t)bh * HEADE + t0;
#pragma unroll
        for (int i = 0; i < 2; i++) {
            const int d = (tid >> 3) + 32 * i;
            const int c = tid & 7;
            float t[8];
#pragma unroll
            for (int j = 0; j < 8; j++) t[j] = tile[c * 8 + j][d];
            *(short8*)(dst + (size_t)d * Tc + c * 8) = pack8(t);
        }
    }
}

__global__ __launch_bounds__(512, 4)
void dswa_kernel(const float* __restrict__ Q,
                 const unsigned short* __restrict__ Kb,
                 const unsigned short* __restrict__ Vtb,
                 const int* __restrict__ wsz,
                 float* __restrict__ O, unsigned* __restrict__ counter) {
    __shared__ __align__(16) unsigned short LDS[24576 + 8];

    const int tid  = threadIdx.x;
    const int g    = tid >> 8;          // kv-split group 0/1
    const int ltid = tid & 255;
    const int wave = tid >> 6;
    const int wv   = wave & 3;          // q-row group
    const int lane = tid & 63;
    const int quad = lane >> 4;
    const int l16  = lane & 15;
    const int sw8  = (l16 & 7) << 3;    // fragment-read swizzle term

    unsigned short* Kl = &LDS[KOFF + g * 4096];
    unsigned short* Vt = &LDS[VOFF + g * 4096];
    unsigned short* Pl = &LDS[POFF + wave * 1024];
    int* ib = (int*)&LDS[IBOFF];

    const int srow = ltid >> 3;         // staging row 0..31 (+32)
    const int scol = (ltid & 7) * 8;

    for (;;) {
        if (tid == 0) *ib = (int)atomicAdd(counter, 1u);
        __syncthreads();
        const int idx = *ib;
        if (idx >= N_ITEMS) break;

        // heavy-first: h descending (largest window first), qt descending
        const int b  = idx & 1;
        const int qt = 31 - ((idx >> 1) & 31);
        const int h  = 15 - (idx >> 6);
        const int q0 = qt * BQ;
        const int win = wsz[h];

        const size_t headoff = (size_t)(b * Hc + h) * HEADE;
        const float* Qp = Q + headoff;
        const unsigned short* Kbh = Kb + headoff;
        const unsigned short* Vbh = Vtb + headoff;
        float* Op = O + headoff;

        // ---- Q fragments, pre-scaled (log2 domain) ----
        short8 qf[2];
        {
            const int qrow = q0 + wv * 16 + l16;
#pragma unroll
            for (int c = 0; c < 2; c++) {
                const float* src = Qp + (size_t)qrow * Dc + c * 32 + quad * 8;
                float4v a = *(const float4v*)src;
                float4v d4 = *(const float4v*)(src + 4);
                float t[8] = {a[0]*QSCALE, a[1]*QSCALE, a[2]*QSCALE, a[3]*QSCALE,
                              d4[0]*QSCALE, d4[1]*QSCALE, d4[2]*QSCALE, d4[3]*QSCALE};
                qf[c] = pack8(t);
            }
        }

        float4v acc[4];   // O accumulator (unnormalized)
#pragma unroll
        for (int nb = 0; nb < 4; nb++) acc[nb] = (float4v){0.f, 0.f, 0.f, 0.f};
        float lp = 0.0f;  // per-lane l partial (qrow = l16; this quad's keys)

        const int kv_lo = (max(0, q0 - win)) & ~(BK - 1);
        const int n_tiles = (q0 + BQ - kv_lo) >> 6;
        const int IT = (n_tiles + 1) >> 1;

        const int rw0 = q0 + wv * 16;
        const int rg_rel0 = rw0 + l16 - quad * 4;

        // ---- prologue prefetch: tile g into registers ----
        short8 kr0, kr1, vr0, vr1;
        if (g < n_tiles) {
            const int kv0 = kv_lo + g * BK;
            kr0 = *(const short8*)(Kbh + (size_t)(kv0 + srow) * Dc + scol);
            kr1 = *(const short8*)(Kbh + (size_t)(kv0 + srow + 32) * Dc + scol);
            vr0 = *(const short8*)(Vbh + (size_t)srow * Tc + kv0 + scol);
            vr1 = *(const short8*)(Vbh + (size_t)(srow + 32) * Tc + kv0 + scol);
        }

        for (int t = 0; t < IT; ++t) {
            const int ti = g + 2 * t;
            const bool act = ti < n_tiles;
            const int kv0 = kv_lo + ti * BK;

            __syncthreads();   // prev iteration's LDS reads complete

            if (act) {
                *(short8*)&Kl[swz(srow, scol)] = kr0;
                *(short8*)&Kl[swz(srow + 32, scol)] = kr1;
                *(short8*)&Vt[swz(srow, scol)] = vr0;
                *(short8*)&Vt[swz(srow + 32, scol)] = vr1;
            }
            __syncthreads();

            // prefetch next tile (overlaps compute)
            const int tn = ti + 2;
            if (tn < n_tiles) {
                const int kvn = kv_lo + tn * BK;
                kr0 = *(const short8*)(Kbh + (size_t)(kvn + srow) * Dc + scol);
                kr1 = *(const short8*)(Kbh + (size_t)(kvn + srow + 32) * Dc + scol);
                vr0 = *(const short8*)(Vbh + (size_t)srow * Tc + kvn + scol);
                vr1 = *(const short8*)(Vbh + (size_t)(srow + 32) * Tc + kvn + scol);
            }

            if (act) {
                // ---- S^T = K Q^T - CMAX (acc-init fold) ----
                float4v sT[4];
#pragma unroll
                for (int mb = 0; mb < 4; mb++) {
                    float4v c = {-CMAX, -CMAX, -CMAX, -CMAX};
#pragma unroll
                    for (int ch = 0; ch < 2; ch++) {
                        short8 kf = *(short8*)&Kl[(mb * 16 + l16) * 64 +
                                                  ((ch * 32 + quad * 8) ^ sw8)];
                        c = __builtin_amdgcn_mfma_f32_16x16x32_bf16(kf, qf[ch], c, 0, 0, 0);
                    }
                    sT[mb] = c;
                }

                // ---- mask only on boundary tiles (wave-uniform test) ----
                const bool interior = (rw0 >= kv0 + 63) && (rw0 + 15 - kv0 <= win);
                if (!interior) {
                    const int dbase = rg_rel0 - kv0;
#pragma unroll
                    for (int mb = 0; mb < 4; mb++)
#pragma unroll
                        for (int r = 0; r < 4; r++) {
                            const unsigned diff = (unsigned)(dbase - mb * 16 - r);
                            sT[mb][r] = (diff <= (unsigned)win) ? sT[mb][r] : -3.0e38f;
                        }
                }

                // ---- p = exp2(s'); l partial; pack P to LDS ----
#pragma unroll
                for (int mb = 0; mb < 4; mb++) {
                    float p0 = EXP2(sT[mb][0]);
                    float p1 = EXP2(sT[mb][1]);
                    float p2 = EXP2(sT[mb][2]);
                    float p3 = EXP2(sT[mb][3]);
                    lp += (p0 + p1) + (p2 + p3);
                    unsigned* dst = (unsigned*)&Pl[l16 * 64 +
                                                   ((mb * 16 + quad * 4) ^ sw8)];
                    dst[0] = pk_bf16(p0, p1);
                    dst[1] = pk_bf16(p2, p3);
                }

                // ---- P (C-layout) -> A-layout via per-wave LDS ----
                __asm__ volatile("" ::: "memory");
                short8 pf[2];
#pragma unroll
                for (int ch = 0; ch < 2; ch++)
                    pf[ch] = *(short8*)&Pl[l16 * 64 + ((ch * 32 + quad * 8) ^ sw8)];

                // ---- O += P V ----
#pragma unroll
                for (int nb = 0; nb < 4; nb++) {
#pragma unroll
                    for (int ch = 0; ch < 2; ch++) {
                        short8 vf = *(short8*)&Vt[(nb * 16 + l16) * 64 +
                                                  ((ch * 32 + quad * 8) ^ sw8)];
                        acc[nb] = __builtin_amdgcn_mfma_f32_16x16x32_bf16(pf[ch], vf, acc[nb], 0, 0, 0);
                    }
                }
            }
        }

        // ---- l: one cross-quad reduce ----
        lp += __shfl_xor(lp, 16);
        lp += __shfl_xor(lp, 32);

        // ---- merge the two KV-split partials (pure adds), store ----
        __syncthreads();
        float* fl = (float*)LDS;   // 64 rows x stride 66: cols 0..63 = O, 64 = l
        if (g == 1) {
            if (quad == 0) fl[(wv * 16 + l16) * 66 + 64] = lp;
#pragma unroll
            for (int r = 0; r < 4; r++) {
                const int row = wv * 16 + quad * 4 + r;
#pragma unroll
                for (int nb = 0; nb < 4; nb++)
                    fl[row * 66 + nb * 16 + l16] = acc[nb][r];
            }
        }
        __syncthreads();
        if (g == 0) {
#pragma unroll
            for (int r = 0; r < 4; r++) {
                const int row = wv * 16 + quad * 4 + r;
                const float l0 = __shfl(lp, quad * 4 + r);
                const float lt = l0 + fl[row * 66 + 64];
                const float inv = 1.0f / lt;
                float* dst = Op + (size_t)(q0 + row) * Dc;
#pragma unroll
                for (int nb = 0; nb < 4; nb++)
                    dst[nb * 16 + l16] = (acc[nb][r] + fl[row * 66 + nb * 16 + l16]) * inv;
            }
        }
        // next item's post-atomic barrier protects fl before reuse
    }
}

extern "C" void kernel_launch(void* const* d_in, const int* in_sizes, int n_in,
                              void* d_out, int out_size, void* d_ws, size_t ws_size,
                              hipStream_t stream) {
    (void)in_sizes; (void)n_in; (void)ws_size; (void)out_size;
    const float* Q = (const float*)d_in[0];
    const float* K = (const float*)d_in[1];
    const float* V = (const float*)d_in[2];
    const int* wsz = (const int*)d_in[3];
    float* Out = (float*)d_out;

    unsigned* counter = (unsigned*)d_ws;
    unsigned short* Kb  = (unsigned short*)((char*)d_ws + KB_OFF);
    unsigned short* Vtb = (unsigned short*)((char*)d_ws + VB_OFF);

    hipMemsetAsync(counter, 0, sizeof(unsigned), stream);
    preconv_kernel<<<dim3(3072), dim3(256), 0, stream>>>(K, V, Kb, Vtb);
    // 768 blocks = 3 blocks/CU x 256 CU (LDS 49.2 KB); work-stealing body.
    dswa_kernel<<<dim3(768), dim3(512), 0, stream>>>(Q, Kb, Vtb, wsz, Out, counter);
}

// Round 9
// 126.256 us; speedup vs baseline: 2.1222x; 1.0193x over previous
//
#include <hip/hip_runtime.h>
#include <hip/hip_bf16.h>

// DynamicSlidingWindowAttention — flash attention, bf16 MFMA, gfx950.
// R9 = R8 with single-barrier double-buffered staging: per tile,
//   write regs->buf[t&1]; __syncthreads; prefetch t+2; compute buf[t&1].
// One rendezvous/tile (was 2), vmcnt already drained at the barrier (the
// prefetch is consumed by the staging write right before it). LDS grows to
// 80 KB -> 2 blocks/CU (was 3); betting halved convoy beats occupancy loss.
// Kept from R8: persistent blocks + work-stealing heavy-first, 2-way KV
// split, prestaged bf16 K / V^T in d_ws, XOR-swizzled LDS, static-max
// softmax in log2 domain, launch_bounds(512,4) (R7 spill lesson).
// Layouts (m89/m91/m120-verified):
//   mfma_f32_16x16x32_bf16: A[m=lane&15][k=quad*8+j], B[k=quad*8+j][n=lane&15],
//   C/D: col=lane&15, row=quad*4+reg.

constexpr int Bc = 2, Hc = 16, Tc = 2048, Dc = 64;
constexpr int BQ = 64;
constexpr int BK = 64;
constexpr int N_ITEMS = Bc * Hc * (Tc / BQ);   // 1024
constexpr float QSCALE = 0.125f * 1.44269504088896340736f;  // 1/sqrt(d)*log2e
constexpr float CMAX = 16.0f;   // static softmax max (log2 domain)

// d_ws layout (bytes): [0,4) counter | [256,+8MiB) K bf16 | then V^T bf16
constexpr size_t KB_OFF = 256;
constexpr size_t VB_OFF = 256 + (size_t)Bc * Hc * Tc * Dc * 2;
constexpr int HEADE = Tc * Dc;

// LDS (ushort units), 80 KB exactly -> 2 blocks/CU:
//   K: g*8192 + buf*4096        [0, 16384)
//   V: 16384 + g*8192 + buf*4096 [16384, 32768)
//   P: 32768 + wave*1024         [32768, 40960)
// item broadcast reuses wave-0's P slot (dead at broadcast time).
constexpr int KOFF = 0;
constexpr int VOFF = 16384;
constexpr int POFF = 32768;

typedef __attribute__((ext_vector_type(8))) short short8;
typedef __attribute__((ext_vector_type(4))) float float4v;

#if defined(__has_builtin)
#if __has_builtin(__builtin_amdgcn_exp2f)
#define EXP2 __builtin_amdgcn_exp2f
#endif
#endif
#ifndef EXP2
#define EXP2 exp2f
#endif

__device__ inline unsigned f2bf_u(float f) {
    union { float f; unsigned u; } v; v.f = f;
    return (v.u + 0x7fffu + ((v.u >> 16) & 1u)) >> 16;   // RNE
}

__device__ inline short8 pack8(const float* t) {
    short8 r;
#pragma unroll
    for (int j = 0; j < 8; j++) r[j] = (short)f2bf_u(t[j]);
    return r;
}

__device__ inline unsigned pk_bf16(float a, float b) {
    __hip_bfloat162 h = __float22bfloat162_rn(make_float2(a, b));
    union { __hip_bfloat162 h; unsigned u; } v; v.h = h;
    return v.u;
}

// XOR swizzle: row-major stride 64 (ushorts), 8-element granule rotated by
// (row&7) — breaks 16-way conflicts of unpadded stride-64, keeps 16B reads.
__device__ inline int swz(int row, int col8) {
    return row * 64 + (col8 ^ ((row & 7) << 3));
}

// ---- pre-pass: K convert + V transpose-convert ----
__global__ __launch_bounds__(256)
void preconv_kernel(const float* __restrict__ K, const float* __restrict__ V,
                    unsigned short* __restrict__ Kb, unsigned short* __restrict__ Vtb) {
    const int blk = blockIdx.x;
    const int tid = threadIdx.x;
    if (blk < 2048) {
        const int base = blk * 2048 + tid * 8;
        float4v a = *(const float4v*)(K + base);
        float4v b = *(const float4v*)(K + base + 4);
        float t[8] = {a[0], a[1], a[2], a[3], b[0], b[1], b[2], b[3]};
        *(short8*)(Kb + base) = pack8(t);
    } else {
        __shared__ float tile[64][65];
        const int blk2 = blk - 2048;
        const int bh = blk2 >> 5;
        const int t0 = (blk2 & 31) * 64;
        const float* src = V + (size_t)bh * HEADE + (size_t)t0 * Dc;
#pragma unroll
        for (int i = 0; i < 4; i++) {
            const int r = (tid >> 4) + i * 16;
            const int d4 = (tid & 15) * 4;
            float4v v4 = *(const float4v*)(src + r * Dc + d4);
            tile[r][d4] = v4[0]; tile[r][d4 + 1] = v4[1];
            tile[r][d4 + 2] = v4[2]; tile[r][d4 + 3] = v4[3];
        }
        __syncthreads();
        unsigned short* dst = Vtb + (size_t)bh * HEADE + t0;
#pragma unroll
        for (int i = 0; i < 2; i++) {
            const int d = (tid >> 3) + 32 * i;
            const int c = tid & 7;
            float t[8];
#pragma unroll
            for (int j = 0; j < 8; j++) t[j] = tile[c * 8 + j][d];
            *(short8*)(dst + (size_t)d * Tc + c * 8) = pack8(t);
        }
    }
}

__global__ __launch_bounds__(512, 4)
void dswa_kernel(const float* __restrict__ Q,
                 const unsigned short* __restrict__ Kb,
                 const unsigned short* __restrict__ Vtb,
                 const int* __restrict__ wsz,
                 float* __restrict__ O, unsigned* __restrict__ counter) {
    __shared__ __align__(16) unsigned short LDS[40960];   // 80 KB

    const int tid  = threadIdx.x;
    const int g    = tid >> 8;          // kv-split group 0/1
    const int ltid = tid & 255;
    const int wave = tid >> 6;
    const int wv   = wave & 3;          // q-row group
    const int lane = tid & 63;
    const int quad = lane >> 4;
    const int l16  = lane & 15;
    const int sw8  = (l16 & 7) << 3;    // fragment-read swizzle term

    unsigned short* Kg = &LDS[KOFF + g * 8192];   // + buf*4096
    unsigned short* Vg = &LDS[VOFF + g * 8192];   // + buf*4096
    unsigned short* Pl = &LDS[POFF + wave * 1024];
    int* ib = (int*)&LDS[POFF];   // overlays wave-0 P (dead at broadcast time)

    const int srow = ltid >> 3;         // staging row 0..31 (+32)
    const int scol = (ltid & 7) * 8;

    for (;;) {
        if (tid == 0) *ib = (int)atomicAdd(counter, 1u);
        __syncthreads();
        const int idx = *ib;
        if (idx >= N_ITEMS) break;

        // heavy-first: h descending (largest window first), qt descending
        const int b  = idx & 1;
        const int qt = 31 - ((idx >> 1) & 31);
        const int h  = 15 - (idx >> 6);
        const int q0 = qt * BQ;
        const int win = wsz[h];

        const size_t headoff = (size_t)(b * Hc + h) * HEADE;
        const float* Qp = Q + headoff;
        const unsigned short* Kbh = Kb + headoff;
        const unsigned short* Vbh = Vtb + headoff;
        float* Op = O + headoff;

        // ---- Q fragments, pre-scaled (log2 domain) ----
        short8 qf[2];
        {
            const int qrow = q0 + wv * 16 + l16;
#pragma unroll
            for (int c = 0; c < 2; c++) {
                const float* src = Qp + (size_t)qrow * Dc + c * 32 + quad * 8;
                float4v a = *(const float4v*)src;
                float4v d4 = *(const float4v*)(src + 4);
                float t[8] = {a[0]*QSCALE, a[1]*QSCALE, a[2]*QSCALE, a[3]*QSCALE,
                              d4[0]*QSCALE, d4[1]*QSCALE, d4[2]*QSCALE, d4[3]*QSCALE};
                qf[c] = pack8(t);
            }
        }

        float4v acc[4];   // O accumulator (unnormalized)
#pragma unroll
        for (int nb = 0; nb < 4; nb++) acc[nb] = (float4v){0.f, 0.f, 0.f, 0.f};
        float lp = 0.0f;  // per-lane l partial

        const int kv_lo = (max(0, q0 - win)) & ~(BK - 1);
        const int n_tiles = (q0 + BQ - kv_lo) >> 6;
        const int IT = (n_tiles + 1) >> 1;

        const int rw0 = q0 + wv * 16;
        const int rg_rel0 = rw0 + l16 - quad * 4;

        // ---- prologue prefetch: tile g into registers ----
        short8 kr0, kr1, vr0, vr1;
        if (g < n_tiles) {
            const int kv0 = kv_lo + g * BK;
            kr0 = *(const short8*)(Kbh + (size_t)(kv0 + srow) * Dc + scol);
            kr1 = *(const short8*)(Kbh + (size_t)(kv0 + srow + 32) * Dc + scol);
            vr0 = *(const short8*)(Vbh + (size_t)srow * Tc + kv0 + scol);
            vr1 = *(const short8*)(Vbh + (size_t)(srow + 32) * Tc + kv0 + scol);
        }

        for (int t = 0; t < IT; ++t) {
            const int ti = g + 2 * t;
            const bool act = ti < n_tiles;
            const int kv0 = kv_lo + ti * BK;
            unsigned short* Kl = Kg + (t & 1) * 4096;
            unsigned short* Vt = Vg + (t & 1) * 4096;

            // ---- stage tile ti into buf[t&1] (consumes prefetch regs) ----
            if (act) {
                *(short8*)&Kl[swz(srow, scol)] = kr0;
                *(short8*)&Kl[swz(srow + 32, scol)] = kr1;
                *(short8*)&Vt[swz(srow, scol)] = vr0;
                *(short8*)&Vt[swz(srow + 32, scol)] = vr1;
            }
            // Single rendezvous: vmcnt already 0 (regs consumed above);
            // drain is lgkm-only. Writes for t+1 (other buffer) will overlap
            // stragglers' compute of t.
            __syncthreads();

            // ---- issue prefetch of tile ti+2 (flies during compute) ----
            const int tn = ti + 2;
            if (tn < n_tiles) {
                const int kvn = kv_lo + tn * BK;
                kr0 = *(const short8*)(Kbh + (size_t)(kvn + srow) * Dc + scol);
                kr1 = *(const short8*)(Kbh + (size_t)(kvn + srow + 32) * Dc + scol);
                vr0 = *(const short8*)(Vbh + (size_t)srow * Tc + kvn + scol);
                vr1 = *(const short8*)(Vbh + (size_t)(srow + 32) * Tc + kvn + scol);
            }

            if (act) {
                // ---- S^T = K Q^T - CMAX (acc-init fold) ----
                float4v sT[4];
#pragma unroll
                for (int mb = 0; mb < 4; mb++) {
                    float4v c = {-CMAX, -CMAX, -CMAX, -CMAX};
#pragma unroll
                    for (int ch = 0; ch < 2; ch++) {
                        short8 kf = *(short8*)&Kl[(mb * 16 + l16) * 64 +
                                                  ((ch * 32 + quad * 8) ^ sw8)];
                        c = __builtin_amdgcn_mfma_f32_16x16x32_bf16(kf, qf[ch], c, 0, 0, 0);
                    }
                    sT[mb] = c;
                }

                // ---- mask only on boundary tiles (wave-uniform test) ----
                const bool interior = (rw0 >= kv0 + 63) && (rw0 + 15 - kv0 <= win);
                if (!interior) {
                    const int dbase = rg_rel0 - kv0;
#pragma unroll
                    for (int mb = 0; mb < 4; mb++)
#pragma unroll
                        for (int r = 0; r < 4; r++) {
                            const unsigned diff = (unsigned)(dbase - mb * 16 - r);
                            sT[mb][r] = (diff <= (unsigned)win) ? sT[mb][r] : -3.0e38f;
                        }
                }

                // ---- p = exp2(s'); l partial; pack P to LDS ----
#pragma unroll
                for (int mb = 0; mb < 4; mb++) {
                    float p0 = EXP2(sT[mb][0]);
                    float p1 = EXP2(sT[mb][1]);
                    float p2 = EXP2(sT[mb][2]);
                    float p3 = EXP2(sT[mb][3]);
                    lp += (p0 + p1) + (p2 + p3);
                    unsigned* dst = (unsigned*)&Pl[l16 * 64 +
                                                   ((mb * 16 + quad * 4) ^ sw8)];
                    dst[0] = pk_bf16(p0, p1);
                    dst[1] = pk_bf16(p2, p3);
                }

                // ---- P (C-layout) -> A-layout via per-wave LDS ----
                __asm__ volatile("" ::: "memory");
                short8 pf[2];
#pragma unroll
                for (int ch = 0; ch < 2; ch++)
                    pf[ch] = *(short8*)&Pl[l16 * 64 + ((ch * 32 + quad * 8) ^ sw8)];

                // ---- O += P V ----
#pragma unroll
                for (int nb = 0; nb < 4; nb++) {
#pragma unroll
                    for (int ch = 0; ch < 2; ch++) {
                        short8 vf = *(short8*)&Vt[(nb * 16 + l16) * 64 +
                                                  ((ch * 32 + quad * 8) ^ sw8)];
                        acc[nb] = __builtin_amdgcn_mfma_f32_16x16x32_bf16(pf[ch], vf, acc[nb], 0, 0, 0);
                    }
                }
            }
        }

        // ---- l: one cross-quad reduce ----
        lp += __shfl_xor(lp, 16);
        lp += __shfl_xor(lp, 32);

        // ---- merge the two KV-split partials (pure adds), store ----
        __syncthreads();
        float* fl = (float*)LDS;   // 64 rows x stride 66 (overlays K buffers)
        if (g == 1) {
            if (quad == 0) fl[(wv * 16 + l16) * 66 + 64] = lp;
#pragma unroll
            for (int r = 0; r < 4; r++) {
                const int row = wv * 16 + quad * 4 + r;
#pragma unroll
                for (int nb = 0; nb < 4; nb++)
                    fl[row * 66 + nb * 16 + l16] = acc[nb][r];
            }
        }
        __syncthreads();
        if (g == 0) {
#pragma unroll
            for (int r = 0; r < 4; r++) {
                const int row = wv * 16 + quad * 4 + r;
                const float l0 = __shfl(lp, quad * 4 + r);
                const float lt = l0 + fl[row * 66 + 64];
                const float inv = 1.0f / lt;
                float* dst = Op + (size_t)(q0 + row) * Dc;
#pragma unroll
                for (int nb = 0; nb < 4; nb++)
                    dst[nb * 16 + l16] = (acc[nb][r] + fl[row * 66 + nb * 16 + l16]) * inv;
            }
        }
        // next item's post-atomic barrier protects fl before reuse
    }
}

extern "C" void kernel_launch(void* const* d_in, const int* in_sizes, int n_in,
                              void* d_out, int out_size, void* d_ws, size_t ws_size,
                              hipStream_t stream) {
    (void)in_sizes; (void)n_in; (void)ws_size; (void)out_size;
    const float* Q = (const float*)d_in[0];
    const float* K = (const float*)d_in[1];
    const float* V = (const float*)d_in[2];
    const int* wsz = (const int*)d_in[3];
    float* Out = (float*)d_out;

    unsigned* counter = (unsigned*)d_ws;
    unsigned short* Kb  = (unsigned short*)((char*)d_ws + KB_OFF);
    unsigned short* Vtb = (unsigned short*)((char*)d_ws + VB_OFF);

    hipMemsetAsync(counter, 0, sizeof(unsigned), stream);
    preconv_kernel<<<dim3(3072), dim3(256), 0, stream>>>(K, V, Kb, Vtb);
    // 512 blocks = 2 blocks/CU x 256 CU (LDS 80 KB); work-stealing body.
    dswa_kernel<<<dim3(512), dim3(512), 0, stream>>>(Q, Kb, Vtb, wsz, Out, counter);
}